// Round 11
// baseline (305.870 us; speedup 1.0000x reference)
//
#include <hip/hip_runtime.h>
#include <cfloat>

typedef unsigned short u16;
typedef unsigned int   u32;
typedef __attribute__((ext_vector_type(8))) short short8;
typedef __attribute__((ext_vector_type(4))) float float4_;
typedef __attribute__((ext_vector_type(2))) float float2_;

#define NB   2
#define N1   4096
#define N2   32768
#define C1   128
#define C2   64
#define CIN  192      // C1 + C2
#define F1   128
#define F2   128
#define ROW0 131      // 3 + C1 (fp32)
#define ROW1 67       // 3 + C2 (fp32)
#define NQ   (NB * N2)   // 65536 total query points
#define EPSF 1e-07f
#define KSPLIT 8
#define KCH  (N1 / KSPLIT)   // 512 candidates per tile
#define PADX 200      // LDS x-tile pitch (u16)
#define PADH 136      // LDS h-tile pitch (u16)

// round-to-nearest-even fp32 -> bf16 (finite data only)
__device__ __forceinline__ u16 f2bf(float f) {
  u32 x = __float_as_uint(f);
  return (u16)((x + 0x7fffu + ((x >> 16) & 1u)) >> 16);
}

// Packed-fp32 distance for a candidate PAIR. Exact numpy order per half:
// d = (dx*dx + dy*dy) + dz*dz, sub = add(neg) (IEEE-identical), all RNE.
__device__ __forceinline__ float2_ pair_dist(float2_ qx, float2_ qy, float2_ qz,
                                             float2_ cx, float2_ cy, float2_ cz) {
  float2_ dx, dy, dz, mx, my, mz;
  asm volatile(
    "v_pk_add_f32 %0, %6, %9  neg_lo:[0,1] neg_hi:[0,1]\n\t"  // dx = qx - cx
    "v_pk_add_f32 %1, %7, %10 neg_lo:[0,1] neg_hi:[0,1]\n\t"  // dy = qy - cy
    "v_pk_add_f32 %2, %8, %11 neg_lo:[0,1] neg_hi:[0,1]\n\t"  // dz = qz - cz
    "v_pk_mul_f32 %3, %0, %0\n\t"                             // dx*dx
    "v_pk_mul_f32 %4, %1, %1\n\t"                             // dy*dy
    "v_pk_mul_f32 %5, %2, %2\n\t"                             // dz*dz
    "v_pk_add_f32 %3, %3, %4\n\t"                             // dx2+dy2
    "v_pk_add_f32 %3, %3, %5\n\t"                             // +dz2
    : "=&v"(dx), "=&v"(dy), "=&v"(dz), "=&v"(mx), "=&v"(my), "=&v"(mz)
    : "v"(qx), "v"(qy), "v"(qz), "v"(cx), "v"(cy), "v"(cz));
  return mx;
}

// Stable top-3 insert, min/med3 distance path + cndmask index path.
// Predicates identical to strict-< stable insert (earlier index wins ties).
__device__ __forceinline__ void ins3m(float d, int gi,
    float& d0, float& d1, float& d2, int& i0, int& i1, int& i2) {
  bool lt0 = d < d0, lt1 = d < d1, lt2 = d < d2;
  float nd0 = fminf(d0, d);
  float nd1 = __builtin_amdgcn_fmed3f(d0, d1, d);
  float nd2 = __builtin_amdgcn_fmed3f(d1, d2, d);
  i2 = lt1 ? i1 : (lt2 ? gi : i2);
  i1 = lt0 ? i0 : (lt1 ? gi : i1);
  i0 = lt0 ? gi : i0;
  d0 = nd0; d1 = nd1; d2 = nd2;
}

// branchless stable top-3 (merge kernel; cold path)
__device__ __forceinline__ void ins3b(float d, int gi,
    float& d0, float& d1, float& d2, int& i0, int& i1, int& i2) {
  bool lt0 = d < d0, lt1 = d < d1, lt2 = d < d2;
  d2 = lt1 ? d1 : (lt2 ? d : d2);
  i2 = lt1 ? i1 : (lt2 ? gi : i2);
  d1 = lt0 ? d0 : (lt1 ? d : d1);
  i1 = lt0 ? i0 : (lt1 ? gi : i1);
  d0 = lt0 ? d : d0;
  i0 = lt0 ? gi : i0;
}

struct Part { float d0, d1, d2; int i0, i1, i2; };   // 24 B
struct KW   { int i0, i1, i2; float w0, w1, w2; };   // 24 B

// ---- repack: fp32 weights -> transposed bf16 (80 KB of ws) ---------------------
__global__ void repack_w(const float* __restrict__ W1, const float* __restrict__ W2,
                         u16* __restrict__ W1t, u16* __restrict__ W2t) {
  int i = blockIdx.x * 256 + threadIdx.x;
  if (i < F1 * CIN) { int n = i / CIN, k = i % CIN; W1t[i] = f2bf(W1[k * F1 + n]); }
  if (i < F2 * F1)  { int n = i / F1,  k = i % F1;  W2t[i] = f2bf(W2[k * F2 + n]); }
}

// ---- K1: kNN partial top-3, candidate pairs via packed fp32 --------------------
// grid (NQ/256, KSPLIT) = 2048 blocks -> 8 blocks/CU, 32 waves/CU.
__global__ __launch_bounds__(256) void knn_part(const float* __restrict__ in0,
                                                const float* __restrict__ in1,
                                                Part* __restrict__ part) {
  __shared__ __align__(16) float csx[KCH];   // SoA: broadcast b64 pair reads
  __shared__ __align__(16) float csy[KCH];
  __shared__ __align__(16) float csz[KCH];
  int t = threadIdx.x;
  int q = blockIdx.x * 256 + t;
  int ct = blockIdx.y;
  int b = q >> 15;                            // uniform per block
  int c0 = ct * KCH;
  for (int j = t; j < KCH; j += 256) {
    const float* r = in0 + (size_t)(b * N1 + c0 + j) * ROW0;
    csx[j] = r[0]; csy[j] = r[1]; csz[j] = r[2];
  }
  __syncthreads();
  int n = q & (N2 - 1);
  const float* qr = in1 + (size_t)(b * N2 + n) * ROW1;
  float qx = qr[0], qy = qr[1], qz = qr[2];
  const float2_ qxx = {qx, qx}, qyy = {qy, qy}, qzz = {qz, qz};
  float d0 = FLT_MAX, d1 = FLT_MAX, d2 = FLT_MAX;
  int   i0 = 0, i1 = 0, i2 = 0;
  int   jv = c0;                              // ascending index counter
#pragma unroll 4
  for (int p = 0; p < KCH / 2; p++) {
    float2_ cx = *(const float2_*)&csx[2 * p];
    float2_ cy = *(const float2_*)&csy[2 * p];
    float2_ cz = *(const float2_*)&csz[2 * p];
    float2_ dd = pair_dist(qxx, qyy, qzz, cx, cy, cz);
    ins3m(dd.x, jv,     d0, d1, d2, i0, i1, i2);
    ins3m(dd.y, jv + 1, d0, d1, d2, i0, i1, i2);
    jv += 2;
  }
  Part pr; pr.d0 = d0; pr.d1 = d1; pr.d2 = d2; pr.i0 = i0; pr.i1 = i1; pr.i2 = i2;
  part[((size_t)q << 3) + ct] = pr;
}

// ---- K2: merge partials (ascending tile order preserves tie stability) ---------
__global__ __launch_bounds__(256) void knn_merge(const Part* __restrict__ part,
                                                 KW* __restrict__ kw) {
  int q = blockIdx.x * 256 + threadIdx.x;
  float d0 = FLT_MAX, d1 = FLT_MAX, d2 = FLT_MAX;
  int   i0 = 0, i1 = 0, i2 = 0;
#pragma unroll
  for (int ct = 0; ct < KSPLIT; ct++) {
    Part p = part[((size_t)q << 3) + ct];
    ins3b(p.d0, p.i0, d0, d1, d2, i0, i1, i2);
    ins3b(p.d1, p.i1, d0, d1, d2, i0, i1, i2);
    ins3b(p.d2, p.i2, d0, d1, d2, i0, i1, i2);
  }
  float a0 = fmaxf(d0, EPSF), a1 = fmaxf(d1, EPSF), a2 = fmaxf(d2, EPSF);
  float w0 = 1.f / a0, w1 = 1.f / a1, w2 = 1.f / a2;
  float s = __fadd_rn(__fadd_rn(w0, w1), w2);
  KW o; o.i0 = i0; o.i1 = i1; o.i2 = i2;
  o.w0 = w0 / s; o.w1 = w1 / s; o.w2 = w2 / s;
  kw[q] = o;
}

// ---- K3: interp + concat -> bf16 LDS -> MFMA MLP1 -> MFMA MLP2 -> fp32 out -----
// block = 256 = 4 waves; each wave owns 16 query rows. 1024 blocks.
__global__ __launch_bounds__(256) void interp_mlp(
    const float* __restrict__ in0, const float* __restrict__ in1,
    const KW* __restrict__ kw,
    const u16* __restrict__ W1t, const float* __restrict__ b1,
    const u16* __restrict__ W2t, const float* __restrict__ b2,
    float* __restrict__ out) {
  __shared__ __align__(16) u16 xs[4][16][PADX];   // 25,600 B
  __shared__ __align__(16) u16 hs[4][16][PADH];   // 17,408 B
  int t = threadIdx.x;
  int wave = t >> 6, lane = t & 63;
  int l16 = lane & 15, quad = lane >> 4;
  int qbase = blockIdx.x * 64 + wave * 16;
  int b = qbase >> 15;                  // uniform per block

  // preload all 16 KW structs (independent loads -> pipelined)
  KW kreg[16];
#pragma unroll
  for (int qi = 0; qi < 16; qi++) kreg[qi] = kw[qbase + qi];

  // interp + concat into xs[wave] (16 x 192), fp32 gather, bf16 pack
  const float* base = in0 + (size_t)b * N1 * ROW0 + 3;
#pragma unroll 4
  for (int qi = 0; qi < 16; qi++) {
    KW k = kreg[qi];
    const float* r0 = base + (size_t)k.i0 * ROW0;
    const float* r1 = base + (size_t)k.i1 * ROW0;
    const float* r2 = base + (size_t)k.i2 * ROW0;
    float lo = fmaf(k.w2, r2[lane],      fmaf(k.w1, r1[lane],      k.w0 * r0[lane]));
    float hi = fmaf(k.w2, r2[64 + lane], fmaf(k.w1, r1[64 + lane], k.w0 * r0[64 + lane]));
    xs[wave][qi][lane]      = f2bf(lo);
    xs[wave][qi][64 + lane] = f2bf(hi);
    int n2 = (qbase + qi) & (N2 - 1);   // channels 128..191 = points2
    xs[wave][qi][C1 + lane] = f2bf(in1[(size_t)(b * N2 + n2) * ROW1 + 3 + lane]);
  }
  __syncthreads();

  // GEMM1: h = relu(x @ W1 + b1); A from LDS, B from global (L1/L2-resident)
  float4_ acc[8];
#pragma unroll
  for (int nt = 0; nt < 8; nt++) acc[nt] = (float4_)0.f;
#pragma unroll
  for (int k0 = 0; k0 < CIN; k0 += 32) {
    short8 af = *(const short8*)&xs[wave][l16][k0 + quad * 8];
#pragma unroll
    for (int nt = 0; nt < 8; nt++) {
      short8 bf = *(const short8*)(W1t + (size_t)(nt * 16 + l16) * CIN + k0 + quad * 8);
      acc[nt] = __builtin_amdgcn_mfma_f32_16x16x32_bf16(af, bf, acc[nt], 0, 0, 0);
    }
  }
#pragma unroll
  for (int nt = 0; nt < 8; nt++) {
    float bv = b1[nt * 16 + l16];
#pragma unroll
    for (int r = 0; r < 4; r++) {   // C/D: row=quad*4+r, col=nt*16+l16
      hs[wave][quad * 4 + r][nt * 16 + l16] = f2bf(fmaxf(acc[nt][r] + bv, 0.f));
    }
  }
  __syncthreads();

  // GEMM2: y = relu(h @ W2 + b2) -> fp32 global store
  float4_ a2[8];
#pragma unroll
  for (int nt = 0; nt < 8; nt++) a2[nt] = (float4_)0.f;
#pragma unroll
  for (int k0 = 0; k0 < F1; k0 += 32) {
    short8 af = *(const short8*)&hs[wave][l16][k0 + quad * 8];
#pragma unroll
    for (int nt = 0; nt < 8; nt++) {
      short8 bf = *(const short8*)(W2t + (size_t)(nt * 16 + l16) * F1 + k0 + quad * 8);
      a2[nt] = __builtin_amdgcn_mfma_f32_16x16x32_bf16(af, bf, a2[nt], 0, 0, 0);
    }
  }
#pragma unroll
  for (int nt = 0; nt < 8; nt++) {
    float bv = b2[nt * 16 + l16];
#pragma unroll
    for (int r = 0; r < 4; r++) {
      int row = qbase + quad * 4 + r;
      out[(size_t)row * F2 + nt * 16 + l16] = fmaxf(a2[nt][r] + bv, 0.f);
    }
  }
}

// ---- K4: xyz2 passthrough fp32 -> fp32 -----------------------------------------
__global__ void xyz_copy(const float* __restrict__ in1, float* __restrict__ out) {
  int q = blockIdx.x * blockDim.x + threadIdx.x;
  if (q < NQ) {
    const float* r = in1 + (size_t)q * ROW1;
    float* o = out + (size_t)NQ * F2 + (size_t)q * 3;
    o[0] = r[0]; o[1] = r[1]; o[2] = r[2];
  }
}

extern "C" void kernel_launch(void* const* d_in, const int* in_sizes, int n_in,
                              void* d_out, int out_size, void* d_ws, size_t ws_size,
                              hipStream_t stream) {
  // input assignment by element count (ordering-invariant); positional fallback
  const float *in0 = nullptr, *in1 = nullptr, *W1 = nullptr, *W2 = nullptr;
  const float *b1 = nullptr, *b2 = nullptr;
  for (int i = 0; i < n_in; i++) {
    const float* p = (const float*)d_in[i];
    switch (in_sizes[i]) {
      case 2 * N1 * ROW0: in0 = p; break;
      case 2 * N2 * ROW1: in1 = p; break;
      case CIN * F1:      W1  = p; break;
      case F1 * F2:       W2  = p; break;
      case F1:            (b1 ? b2 : b1) = p; break;
      default: break;
    }
  }
  if (!in0) in0 = (const float*)d_in[0];
  if (!in1) in1 = (const float*)d_in[1];
  if (!W1)  W1  = (const float*)d_in[2];
  if (!b1)  b1  = (const float*)d_in[3];
  if (!W2)  W2  = (const float*)d_in[4];
  if (!b2)  b2  = (const float*)d_in[5];

  float* out = (float*)d_out;   // fp32: x (65536*128) ++ xyz2 (65536*3)

  // ws: W1t 49,152 | W2t 32,768 | kw 1,572,864 | part 12,582,912  = 13.6 MB
  char* ws = (char*)d_ws;
  u16*  W1t  = (u16*)(ws + 0);
  u16*  W2t  = (u16*)(ws + 49152);
  KW*   kw   = (KW*)(ws + 81920);
  Part* part = (Part*)(ws + 1654784);

  repack_w<<<dim3(96), dim3(256), 0, stream>>>(W1, W2, W1t, W2t);
  knn_part<<<dim3(NQ / 256, KSPLIT), dim3(256), 0, stream>>>(in0, in1, part);
  knn_merge<<<dim3(NQ / 256), dim3(256), 0, stream>>>(part, kw);
  interp_mlp<<<dim3(NQ / 64), dim3(256), 0, stream>>>(in0, in1, kw, W1t, b1, W2t, b2, out);
  xyz_copy<<<dim3((NQ + 255) / 256), dim3(256), 0, stream>>>(in1, out);
}

// Round 12
// 280.865 us; speedup vs baseline: 1.0890x; 1.0890x over previous
//
#include <hip/hip_runtime.h>
#include <cfloat>

typedef unsigned short u16;
typedef unsigned int   u32;
typedef __attribute__((ext_vector_type(8))) short short8;
typedef __attribute__((ext_vector_type(4))) float float4_;
typedef __attribute__((ext_vector_type(2))) float float2_;

#define NB   2
#define N1   4096
#define N2   32768
#define C1   128
#define C2   64
#define CIN  192      // C1 + C2
#define F1   128
#define F2   128
#define ROW0 131      // 3 + C1 (fp32)
#define ROW1 67       // 3 + C2 (fp32)
#define NQ   (NB * N2)   // 65536 total query points
#define EPSF 1e-07f
#define KSPLIT 8
#define KCH  (N1 / KSPLIT)   // 512 candidates per tile
#define PADX 200      // LDS x-tile pitch (u16)
#define PADH 136      // LDS h-tile pitch (u16)

// round-to-nearest-even fp32 -> bf16 (finite data only)
__device__ __forceinline__ u16 f2bf(float f) {
  u32 x = __float_as_uint(f);
  return (u16)((x + 0x7fffu + ((x >> 16) & 1u)) >> 16);
}

// Stable top-3 insert, min/med3 distance path + cndmask index path.
// Case-equivalent to strict-< stable insert (earlier index wins ties):
//  nd0=min(d0,d); with d0<=d1<=d2 invariant, fmed3(d0,d1,d)=min(d1,max(d0,d)),
//  fmed3(d1,d2,d)=min(d2,max(d1,d)) — verified against all 4 insert cases.
__device__ __forceinline__ void ins3m(float d, int gi,
    float& d0, float& d1, float& d2, int& i0, int& i1, int& i2) {
  bool lt0 = d < d0, lt1 = d < d1, lt2 = d < d2;
  float nd0 = fminf(d0, d);
  float nd1 = __builtin_amdgcn_fmed3f(d0, d1, d);
  float nd2 = __builtin_amdgcn_fmed3f(d1, d2, d);
  i2 = lt1 ? i1 : (lt2 ? gi : i2);
  i1 = lt0 ? i0 : (lt1 ? gi : i1);
  i0 = lt0 ? gi : i0;
  d0 = nd0; d1 = nd1; d2 = nd2;
}

// branchless stable top-3 (merge kernel; cold path)
__device__ __forceinline__ void ins3b(float d, int gi,
    float& d0, float& d1, float& d2, int& i0, int& i1, int& i2) {
  bool lt0 = d < d0, lt1 = d < d1, lt2 = d < d2;
  d2 = lt1 ? d1 : (lt2 ? d : d2);
  i2 = lt1 ? i1 : (lt2 ? gi : i2);
  d1 = lt0 ? d0 : (lt1 ? d : d1);
  i1 = lt0 ? i0 : (lt1 ? gi : i1);
  d0 = lt0 ? d : d0;
  i0 = lt0 ? gi : i0;
}

struct Part { float d0, d1, d2; int i0, i1, i2; };   // 24 B
struct KW   { int i0, i1, i2; float w0, w1, w2; };   // 24 B

// ---- repack: fp32 weights -> transposed bf16 (80 KB of ws) ---------------------
__global__ void repack_w(const float* __restrict__ W1, const float* __restrict__ W2,
                         u16* __restrict__ W1t, u16* __restrict__ W2t) {
  int i = blockIdx.x * 256 + threadIdx.x;
  if (i < F1 * CIN) { int n = i / CIN, k = i % CIN; W1t[i] = f2bf(W1[k * F1 + n]); }
  if (i < F2 * F1)  { int n = i / F1,  k = i % F1;  W2t[i] = f2bf(W2[k * F2 + n]); }
}

// ---- K1: kNN partial top-3, candidate pairs via compiler-vectorized fp32 -------
// grid (NQ/256, KSPLIT) = 2048 blocks -> 8 blocks/CU, 32 waves/CU.
__global__ __launch_bounds__(256) void knn_part(const float* __restrict__ in0,
                                                const float* __restrict__ in1,
                                                Part* __restrict__ part) {
#pragma clang fp contract(off)
  // pair-packed SoA: pair p holds {x0,x1,y0,y1} (16B) and {z0,z1} (8B)
  __shared__ __align__(16) float paxy[KCH * 2];   // 4 KB
  __shared__ __align__(16) float paz[KCH];        // 2 KB
  int t = threadIdx.x;
  int q = blockIdx.x * 256 + t;
  int ct = blockIdx.y;
  int b = q >> 15;                            // uniform per block
  int c0 = ct * KCH;
  for (int j = t; j < KCH; j += 256) {
    const float* r = in0 + (size_t)(b * N1 + c0 + j) * ROW0;
    int p = j >> 1, par = j & 1;
    paxy[4 * p + par]     = r[0];
    paxy[4 * p + 2 + par] = r[1];
    paz[j]                = r[2];
  }
  __syncthreads();
  int n = q & (N2 - 1);
  const float* qr = in1 + (size_t)(b * N2 + n) * ROW1;
  float qx = qr[0], qy = qr[1], qz = qr[2];
  const float2_ qxx = {qx, qx}, qyy = {qy, qy}, qzz = {qz, qz};
  float d0 = FLT_MAX, d1 = FLT_MAX, d2 = FLT_MAX;
  int   i0 = 0, i1 = 0, i2 = 0;
#pragma unroll 4
  for (int p = 0; p < KCH / 2; p++) {
    float4_ A = *(const float4_*)&paxy[4 * p];   // ds_read_b128, broadcast
    float2_ Z = *(const float2_*)&paz[2 * p];    // ds_read_b64,  broadcast
    float2_ cx = {A.x, A.y}, cy = {A.z, A.w};
    float2_ dx = qxx - cx, dy = qyy - cy, dz = qzz - Z;
    // contract(off): element-wise RNE, identical to (dx*dx+dy*dy)+dz*dz scalar
    float2_ dd = (dx * dx + dy * dy) + dz * dz;
    int jv = c0 + 2 * p;
    ins3m(dd.x, jv,     d0, d1, d2, i0, i1, i2);
    ins3m(dd.y, jv + 1, d0, d1, d2, i0, i1, i2);
  }
  Part pr; pr.d0 = d0; pr.d1 = d1; pr.d2 = d2; pr.i0 = i0; pr.i1 = i1; pr.i2 = i2;
  part[((size_t)q << 3) + ct] = pr;
}

// ---- K2: merge partials (ascending tile order preserves tie stability) ---------
__global__ __launch_bounds__(256) void knn_merge(const Part* __restrict__ part,
                                                 KW* __restrict__ kw) {
  int q = blockIdx.x * 256 + threadIdx.x;
  float d0 = FLT_MAX, d1 = FLT_MAX, d2 = FLT_MAX;
  int   i0 = 0, i1 = 0, i2 = 0;
#pragma unroll
  for (int ct = 0; ct < KSPLIT; ct++) {
    Part p = part[((size_t)q << 3) + ct];
    ins3b(p.d0, p.i0, d0, d1, d2, i0, i1, i2);
    ins3b(p.d1, p.i1, d0, d1, d2, i0, i1, i2);
    ins3b(p.d2, p.i2, d0, d1, d2, i0, i1, i2);
  }
  float a0 = fmaxf(d0, EPSF), a1 = fmaxf(d1, EPSF), a2 = fmaxf(d2, EPSF);
  float w0 = 1.f / a0, w1 = 1.f / a1, w2 = 1.f / a2;
  float s = __fadd_rn(__fadd_rn(w0, w1), w2);
  KW o; o.i0 = i0; o.i1 = i1; o.i2 = i2;
  o.w0 = w0 / s; o.w1 = w1 / s; o.w2 = w2 / s;
  kw[q] = o;
}

// ---- K3: interp + concat -> bf16 LDS -> MFMA MLP1 -> MFMA MLP2 -> fp32 out -----
// (byte-identical to round-10 version: no kreg preload — VGPR pressure regression)
__global__ __launch_bounds__(256) void interp_mlp(
    const float* __restrict__ in0, const float* __restrict__ in1,
    const KW* __restrict__ kw,
    const u16* __restrict__ W1t, const float* __restrict__ b1,
    const u16* __restrict__ W2t, const float* __restrict__ b2,
    float* __restrict__ out) {
  __shared__ __align__(16) u16 xs[4][16][PADX];   // 25,600 B
  __shared__ __align__(16) u16 hs[4][16][PADH];   // 17,408 B
  int t = threadIdx.x;
  int wave = t >> 6, lane = t & 63;
  int l16 = lane & 15, quad = lane >> 4;
  int qbase = blockIdx.x * 64 + wave * 16;
  int b = qbase >> 15;                  // uniform per block

  // interp + concat into xs[wave] (16 x 192), fp32 gather, bf16 pack
  for (int qi = 0; qi < 16; qi++) {
    int q = qbase + qi;
    KW k = kw[q];                       // wave-uniform load
    const float* base = in0 + (size_t)b * N1 * ROW0 + 3;
    const float* r0 = base + (size_t)k.i0 * ROW0;
    const float* r1 = base + (size_t)k.i1 * ROW0;
    const float* r2 = base + (size_t)k.i2 * ROW0;
    float lo = __fadd_rn(__fadd_rn(__fmul_rn(k.w0, r0[lane]),
                                   __fmul_rn(k.w1, r1[lane])),
                         __fmul_rn(k.w2, r2[lane]));
    float hi = __fadd_rn(__fadd_rn(__fmul_rn(k.w0, r0[64 + lane]),
                                   __fmul_rn(k.w1, r1[64 + lane])),
                         __fmul_rn(k.w2, r2[64 + lane]));
    xs[wave][qi][lane]      = f2bf(lo);
    xs[wave][qi][64 + lane] = f2bf(hi);
    int n2 = q & (N2 - 1);              // channels 128..191 = points2
    xs[wave][qi][C1 + lane] = f2bf(in1[(size_t)(b * N2 + n2) * ROW1 + 3 + lane]);
  }
  __syncthreads();

  // GEMM1: h = relu(x @ W1 + b1); A from LDS, B from global (L1/L2-resident)
  float4_ acc[8];
#pragma unroll
  for (int nt = 0; nt < 8; nt++) acc[nt] = (float4_)0.f;
#pragma unroll
  for (int k0 = 0; k0 < CIN; k0 += 32) {
    short8 af = *(const short8*)&xs[wave][l16][k0 + quad * 8];
#pragma unroll
    for (int nt = 0; nt < 8; nt++) {
      short8 bf = *(const short8*)(W1t + (size_t)(nt * 16 + l16) * CIN + k0 + quad * 8);
      acc[nt] = __builtin_amdgcn_mfma_f32_16x16x32_bf16(af, bf, acc[nt], 0, 0, 0);
    }
  }
#pragma unroll
  for (int nt = 0; nt < 8; nt++) {
    float bv = b1[nt * 16 + l16];
#pragma unroll
    for (int r = 0; r < 4; r++) {   // C/D: row=quad*4+r, col=nt*16+l16
      hs[wave][quad * 4 + r][nt * 16 + l16] = f2bf(fmaxf(acc[nt][r] + bv, 0.f));
    }
  }
  __syncthreads();

  // GEMM2: y = relu(h @ W2 + b2) -> fp32 global store
  float4_ a2[8];
#pragma unroll
  for (int nt = 0; nt < 8; nt++) a2[nt] = (float4_)0.f;
#pragma unroll
  for (int k0 = 0; k0 < F1; k0 += 32) {
    short8 af = *(const short8*)&hs[wave][l16][k0 + quad * 8];
#pragma unroll
    for (int nt = 0; nt < 8; nt++) {
      short8 bf = *(const short8*)(W2t + (size_t)(nt * 16 + l16) * F1 + k0 + quad * 8);
      a2[nt] = __builtin_amdgcn_mfma_f32_16x16x32_bf16(af, bf, a2[nt], 0, 0, 0);
    }
  }
#pragma unroll
  for (int nt = 0; nt < 8; nt++) {
    float bv = b2[nt * 16 + l16];
#pragma unroll
    for (int r = 0; r < 4; r++) {
      int row = qbase + quad * 4 + r;
      out[(size_t)row * F2 + nt * 16 + l16] = fmaxf(a2[nt][r] + bv, 0.f);
    }
  }
}

// ---- K4: xyz2 passthrough fp32 -> fp32 -----------------------------------------
__global__ void xyz_copy(const float* __restrict__ in1, float* __restrict__ out) {
  int q = blockIdx.x * blockDim.x + threadIdx.x;
  if (q < NQ) {
    const float* r = in1 + (size_t)q * ROW1;
    float* o = out + (size_t)NQ * F2 + (size_t)q * 3;
    o[0] = r[0]; o[1] = r[1]; o[2] = r[2];
  }
}

extern "C" void kernel_launch(void* const* d_in, const int* in_sizes, int n_in,
                              void* d_out, int out_size, void* d_ws, size_t ws_size,
                              hipStream_t stream) {
  // input assignment by element count (ordering-invariant); positional fallback
  const float *in0 = nullptr, *in1 = nullptr, *W1 = nullptr, *W2 = nullptr;
  const float *b1 = nullptr, *b2 = nullptr;
  for (int i = 0; i < n_in; i++) {
    const float* p = (const float*)d_in[i];
    switch (in_sizes[i]) {
      case 2 * N1 * ROW0: in0 = p; break;
      case 2 * N2 * ROW1: in1 = p; break;
      case CIN * F1:      W1  = p; break;
      case F1 * F2:       W2  = p; break;
      case F1:            (b1 ? b2 : b1) = p; break;
      default: break;
    }
  }
  if (!in0) in0 = (const float*)d_in[0];
  if (!in1) in1 = (const float*)d_in[1];
  if (!W1)  W1  = (const float*)d_in[2];
  if (!b1)  b1  = (const float*)d_in[3];
  if (!W2)  W2  = (const float*)d_in[4];
  if (!b2)  b2  = (const float*)d_in[5];

  float* out = (float*)d_out;   // fp32: x (65536*128) ++ xyz2 (65536*3)

  // ws: W1t 49,152 | W2t 32,768 | kw 1,572,864 | part 12,582,912  = 13.6 MB
  char* ws = (char*)d_ws;
  u16*  W1t  = (u16*)(ws + 0);
  u16*  W2t  = (u16*)(ws + 49152);
  KW*   kw   = (KW*)(ws + 81920);
  Part* part = (Part*)(ws + 1654784);

  repack_w<<<dim3(96), dim3(256), 0, stream>>>(W1, W2, W1t, W2t);
  knn_part<<<dim3(NQ / 256, KSPLIT), dim3(256), 0, stream>>>(in0, in1, part);
  knn_merge<<<dim3(NQ / 256), dim3(256), 0, stream>>>(part, kw);
  interp_mlp<<<dim3(NQ / 64), dim3(256), 0, stream>>>(in0, in1, kw, W1t, b1, W2t, b2, out);
  xyz_copy<<<dim3((NQ + 255) / 256), dim3(256), 0, stream>>>(in1, out);
}